// Round 5
// baseline (3639.030 us; speedup 1.0000x reference)
//
#include <hip/hip_runtime.h>
#include <math.h>

#define BATCH 64
#define CIN 3
#define IMH 512
#define IMW 512
#define PSZ 16
#define DIM 256
#define GHN 32
#define GWN 32
#define NTOK 1025
#define HID 1024
#define NLAYER 6
#define NCLS 1000
#define LN_EPS 1e-5f

// folded dims: token-fold 513 -> pad 576 ; dim-fold 129 -> pad 144
#define KF 576
#define KR 640           // A rows padded for 128-row tiles (5 x 128)
#define MF 144
#define MROWS 65600      // 64*1025

typedef __attribute__((ext_vector_type(8))) short short8;
typedef __attribute__((ext_vector_type(4))) float f32x4;

#define MFMA16(acc, a, b) acc = __builtin_amdgcn_mfma_f32_16x16x32_bf16(a, b, acc, 0, 0, 0)

// ---------------------------------------------------------------------------
__device__ inline unsigned short rne_bf16(float x) {
    unsigned u = __float_as_uint(x);
    return (unsigned short)((u + 0x7FFF + ((u >> 16) & 1)) >> 16);
}
__device__ inline void split_bf16(float x, unsigned short& hi, unsigned short& lo) {
    unsigned short h = rne_bf16(x);
    hi = h;
    float hf = __uint_as_float((unsigned)h << 16);
    lo = rne_bf16(x - hf);
}
__device__ inline float wave_sum(float v) {
#pragma unroll
    for (int off = 32; off; off >>= 1) v += __shfl_xor(v, off);
    return v;
}
// 64-wide tiles (8 granules/row): perm = g ^ (row&7)  -> 2-way banks (free)
__device__ inline short8 ld8x64(const unsigned short* lds, int row, int q) {
    return *(const short8*)(lds + (row * 8 + (q ^ (row & 7))) * 8);
}
// 32-wide tiles (4 granules/row): perm = g ^ ((row>>1)&3) -> 2-way banks (free)
__device__ inline short8 ld8x32(const unsigned short* lds, int row, int q) {
    return *(const short8*)(lds + (row * 4 + (q ^ ((row >> 1) & 3))) * 8);
}
// async global->LDS 16B (lds arg wave-uniform; HW adds lane*16)
__device__ inline void gl2lds16(const unsigned short* g, unsigned short* l) {
    __builtin_amdgcn_global_load_lds((const __attribute__((address_space(1))) unsigned int*)g,
                                     (__attribute__((address_space(3))) unsigned int*)l, 16, 0, 0);
}
// stage 128 rows x 64 bf16 (mask-7 swizzle); row clamped for M-tail (256 thr)
__device__ inline void a_stage128(unsigned short* lds, const unsigned short* g, int lda, int tid, int maxrow) {
    int lane = tid & 63, w = tid >> 6;
#pragma unroll
    for (int s = 0; s < 4; s++) {
        int slot = w * 256 + s * 64;
        int sl = slot + lane;
        int row = sl >> 3, gc = (sl & 7) ^ (row & 7);
        if (row > maxrow) row = maxrow;
        gl2lds16(g + (size_t)row * lda + gc * 8, lds + slot * 8);
    }
}
// stage 128 rows x 64 bf16, 512-thread variant (2 slots/thread)
__device__ inline void a_stage128_512(unsigned short* lds, const unsigned short* g, int lda, int tid, int maxrow) {
    int lane = tid & 63, w = tid >> 6;
#pragma unroll
    for (int s = 0; s < 2; s++) {
        int slot = w * 128 + s * 64;
        int sl = slot + lane;
        int row = sl >> 3, gc = (sl & 7) ^ (row & 7);
        if (row > maxrow) row = maxrow;
        gl2lds16(g + (size_t)row * lda + gc * 8, lds + slot * 8);
    }
}
// stage 128 rows x 32 bf16 (512 slots, 256 thr x 2)
__device__ inline void b_stage128x32(unsigned short* lds, const unsigned short* g, int lda, int tid) {
    int lane = tid & 63;
#pragma unroll
    for (int s = 0; s < 2; s++) {
        int slot = s * 256 + (tid >> 6) * 64;
        int sl = slot + lane;
        int row = sl >> 2, gc = (sl & 3) ^ ((row >> 1) & 3);
        gl2lds16(g + (size_t)row * lda + gc * 8, lds + slot * 8);
    }
}
// stage 144 rows x 32 bf16 (576 slots: 2 full passes + wave0 partial, 256 thr)
__device__ inline void a_stage144x32(unsigned short* lds, const unsigned short* g, int lda, int tid) {
    int lane = tid & 63, w = tid >> 6;
#pragma unroll
    for (int s = 0; s < 2; s++) {
        int slot = s * 256 + w * 64;
        int sl = slot + lane;
        int row = sl >> 2, gc = (sl & 3) ^ ((row >> 1) & 3);
        gl2lds16(g + (size_t)row * lda + gc * 8, lds + slot * 8);
    }
    if (w == 0) {
        int slot = 512;
        int sl = slot + lane;
        int row = sl >> 2, gc = (sl & 3) ^ ((row >> 1) & 3);
        gl2lds16(g + (size_t)row * lda + gc * 8, lds + slot * 8);
    }
}

// ---------------------------------------------------------------------------
// DFT matrices bf16 hi/lo. C1/S1: [640][576] zero-padded past 512 (rows & cols).
__global__ __launch_bounds__(256) void gen_dft2(unsigned short* C1h, unsigned short* C1l,
                                                unsigned short* S1h, unsigned short* S1l,
                                                unsigned short* C2h, unsigned short* C2l,
                                                unsigned short* S2h, unsigned short* S2l) {
    int idx = blockIdx.x * 256 + threadIdx.x;
    if (idx < KR * KF) {
        int k = idx / KF, n = idx - k * KF;
        float c = 0.f, s = 0.f;
        if (k <= 512 && n <= 512) {
            int r = (k * n) % 1025;
            double ang = 6.283185307179586476925287 * (double)r / 1025.0;
            c = (float)cos(ang); s = (float)sin(ang);
        }
        unsigned short h, l;
        split_bf16(c, h, l); C1h[idx] = h; C1l[idx] = l;
        split_bf16(s, h, l); S1h[idx] = h; S1l[idx] = l;
    }
    if (idx < 256 * 256) {
        int k = idx >> 8, n = idx & 255;
        int r = (k * n) & 255;
        double ang = 6.283185307179586476925287 * (double)r / 256.0;
        float c = (float)cos(ang), s = (float)sin(ang);
        unsigned short h, l;
        split_bf16(c, h, l); C2h[idx] = h; C2l[idx] = l;
        split_bf16(s, h, l); S2h[idx] = h; S2l[idx] = l;
    }
}

// wp hi/lo: conv_w already [d=256][k=768], k = c*256+p*16+q
__global__ __launch_bounds__(256) void conv_wp(const float* __restrict__ w,
                                               unsigned short* __restrict__ wph, unsigned short* __restrict__ wpl) {
    int idx = blockIdx.x * 256 + threadIdx.x;
    unsigned short h, l;
    split_bf16(w[idx], h, l);
    wph[idx] = h; wpl[idx] = l;
}
__global__ __launch_bounds__(256) void conv_w1t(const float* __restrict__ w1, unsigned short* __restrict__ w1t) {
    int idx = blockIdx.x * 256 + threadIdx.x;
    int l = idx / 262144, rem = idx - l * 262144;
    int n = rem >> 8, k = rem & 255;
    w1t[idx] = rne_bf16(w1[(size_t)l * 262144 + (size_t)k * 1024 + n]);
}
__global__ __launch_bounds__(256) void conv_w2t(const float* __restrict__ w2, unsigned short* __restrict__ w2t) {
    int idx = blockIdx.x * 256 + threadIdx.x;
    int l = idx / 262144, rem = idx - l * 262144;
    int n = rem >> 10, k = rem & 1023;
    w2t[idx] = rne_bf16(w2[(size_t)l * 262144 + (size_t)k * 256 + n]);
}

// ---------------------------------------------------------------------------
__global__ __launch_bounds__(256) void cls_init(const float* __restrict__ cls, const float* __restrict__ pos,
                                                float* __restrict__ t) {
    int b = blockIdx.x, tid = threadIdx.x;
    t[(size_t)b * NTOK * DIM + tid] = cls[tid] + pos[tid];
}

// ---------------------------------------------------------------------------
// Fused patch embed: reads x directly, splits hi/lo in-register, 3-pass MFMA.
// M=65536 patches, N=256 dims, K=768. 128x128 tile, BK=32 (32 KB LDS -> 4 blk/CU),
// grid(512,2).
__global__ __launch_bounds__(256) void patch_fused(const float* __restrict__ x,
                                                   const unsigned short* __restrict__ wph,
                                                   const unsigned short* __restrict__ wpl,
                                                   const float* __restrict__ cb, const float* __restrict__ pos,
                                                   float* __restrict__ t) {
    __shared__ __align__(16) unsigned short sAh[4096], sAl[4096], sBh[4096], sBl[4096];
    int m0 = blockIdx.x * 128, n0 = blockIdx.y * 128;
    int tid = threadIdx.x, lane = tid & 63, w = tid >> 6;
    int wr = (w >> 1) * 64, wc = (w & 1) * 64;
    f32x4 z = {0.f, 0.f, 0.f, 0.f};
    f32x4 acc[4][4] = {{z, z, z, z}, {z, z, z, z}, {z, z, z, z}, {z, z, z, z}};
    for (int k0 = 0; k0 < 768; k0 += 32) {
        // A tile: 128 rows x 32 k floats = 1024 float4, 4/thread
#pragma unroll
        for (int s = 0; s < 4; s++) {
            int lin = s * 1024 + tid * 4;
            int row = lin >> 5, kc = lin & 31;
            int m = m0 + row;
            int bb = m >> 10, gh = (m >> 5) & 31, gw = m & 31;
            int k = k0 + kc;
            int c = k >> 8, pp = (k >> 4) & 15, q = k & 15;
            const float* gp = x + (size_t)bb * 786432 + c * 262144 + gh * 8192 + pp * 512 + gw * 16 + q;
            float4 v = *(const float4*)gp;
            ushort4 oh, ol;
            split_bf16(v.x, oh.x, ol.x); split_bf16(v.y, oh.y, ol.y);
            split_bf16(v.z, oh.z, ol.z); split_bf16(v.w, oh.w, ol.w);
            int g = kc >> 3, half = (kc >> 2) & 1;
            int addr = (row * 4 + (g ^ ((row >> 1) & 3))) * 8 + half * 4;
            *(ushort4*)(sAh + addr) = oh;
            *(ushort4*)(sAl + addr) = ol;
        }
        b_stage128x32(sBh, wph + (size_t)n0 * 768 + k0, 768, tid);
        b_stage128x32(sBl, wpl + (size_t)n0 * 768 + k0, 768, tid);
        __syncthreads();
        int q = lane >> 4;
        short8 ah[4], al[4], bh8[4], bl8[4];
#pragma unroll
        for (int i = 0; i < 4; i++) {
            ah[i] = ld8x32(sAh, wr + i * 16 + (lane & 15), q);
            al[i] = ld8x32(sAl, wr + i * 16 + (lane & 15), q);
            bh8[i] = ld8x32(sBh, wc + i * 16 + (lane & 15), q);
            bl8[i] = ld8x32(sBl, wc + i * 16 + (lane & 15), q);
        }
#pragma unroll
        for (int i = 0; i < 4; i++)
#pragma unroll
            for (int j = 0; j < 4; j++) {
                MFMA16(acc[i][j], ah[i], bh8[j]);
                MFMA16(acc[i][j], ah[i], bl8[j]);
                MFMA16(acc[i][j], al[i], bh8[j]);
            }
        __syncthreads();
    }
    int q4 = (lane >> 4) * 4;
#pragma unroll
    for (int i = 0; i < 4; i++) {
        int r = m0 + wr + i * 16 + q4;
#pragma unroll
        for (int j = 0; j < 4; j++) {
            int c = n0 + wc + j * 16 + (lane & 15);
#pragma unroll
            for (int g = 0; g < 4; g++) {
                int rr = r + g;
                int bb = rr >> 10, tok = 1 + (rr & 1023);
                t[((size_t)bb * NTOK + tok) * 256 + c] =
                    acc[i][j][g] + cb[c] + pos[(size_t)tok * 256 + c];
            }
        }
    }
}

// ---------------------------------------------------------------------------
// Per-token LN stats: stats[m] = (mean, rstd). One wave per token.
__global__ __launch_bounds__(256) void ln_stats(const float* __restrict__ t, float2* __restrict__ stats) {
    int wave = threadIdx.x >> 6, lane = threadIdx.x & 63;
    int m = blockIdx.x * 4 + wave;   // < 65600 exact
    const float* row = t + (size_t)m * DIM;
    float4 v = *(const float4*)(row + lane * 4);
    float mean = wave_sum(v.x + v.y + v.z + v.w) * (1.f / 256.f);
    float dx = v.x - mean, dy = v.y - mean, dz = v.z - mean, dw = v.w - mean;
    float sq = wave_sum(dx * dx + dy * dy + dz * dz + dw * dw);
    float rstd = rsqrtf(sq * (1.f / 256.f) + LN_EPS);
    if (lane == 0) stats[m] = make_float2(mean, rstd);
}

// ---------------------------------------------------------------------------
__global__ __launch_bounds__(256) void ln2_bf16(const float* __restrict__ t, unsigned short* __restrict__ hh,
                                                const float* __restrict__ s, const float* __restrict__ bb) {
    int wave = threadIdx.x >> 6, lane = threadIdx.x & 63;
    int m = blockIdx.x * 4 + wave;
    const float* row = t + (size_t)m * DIM;
    float4 v = *(const float4*)(row + lane * 4);
    float mean = wave_sum(v.x + v.y + v.z + v.w) * (1.f / 256.f);
    float dx = v.x - mean, dy = v.y - mean, dz = v.z - mean, dw = v.w - mean;
    float sq = wave_sum(dx * dx + dy * dy + dz * dz + dw * dw);
    float rstd = rsqrtf(sq * (1.f / 256.f) + LN_EPS);
    float4 s4 = *(const float4*)(s + lane * 4);
    float4 b4 = *(const float4*)(bb + lane * 4);
    ushort4 o;
    o.x = rne_bf16(dx * rstd * s4.x + b4.x);
    o.y = rne_bf16(dy * rstd * s4.y + b4.y);
    o.z = rne_bf16(dz * rstd * s4.z + b4.z);
    o.w = rne_bf16(dw * rstd * s4.w + b4.w);
    *(ushort4*)(hh + (size_t)m * DIM + lane * 4) = o;
}

// ---------------------------------------------------------------------------
// Fused LN1 + token-fold + split-bf16 GEMM (3-pass).
// A built in-register from t (normalize via stats, fold +/- by z), B = C2/S2 rows [0..143].
// Output transposed+split O[b][c:144][kp:576] hi/lo. Tile 128x144, BK=32, grid(288, 2).
__global__ __launch_bounds__(256) void fold_gemm(
    const float* __restrict__ tt, const float2* __restrict__ stats,
    const float* __restrict__ ls, const float* __restrict__ lb,
    const unsigned short* __restrict__ C2h, const unsigned short* __restrict__ C2l,
    const unsigned short* __restrict__ S2h, const unsigned short* __restrict__ S2l,
    unsigned short* __restrict__ Ycth, unsigned short* __restrict__ Yctl,
    unsigned short* __restrict__ Ysth, unsigned short* __restrict__ Ystl) {
    __shared__ __align__(16) unsigned short sAh[4096], sAl[4096], sBh[4608], sBl[4608];
    int m0 = blockIdx.x * 128;
    int zz = blockIdx.y;
    const unsigned short* Bh = zz ? S2h : C2h;
    const unsigned short* Bl = zz ? S2l : C2l;
    unsigned short* Oh = zz ? Ysth : Ycth;
    unsigned short* Ol = zz ? Ystl : Yctl;
    int tid = threadIdx.x, lane = tid & 63, w = tid >> 6;
    int wr = w * 32;
    f32x4 zf = {0.f, 0.f, 0.f, 0.f};
    f32x4 acc[2][9];
#pragma unroll
    for (int i = 0; i < 2; i++)
#pragma unroll
        for (int j = 0; j < 9; j++) acc[i][j] = zf;
    for (int k0 = 0; k0 < 256; k0 += 32) {
        // A: 128 rows x 32 dims built from t with LN + fold, split hi/lo
#pragma unroll
        for (int s = 0; s < 4; s++) {
            int sl = tid + s * 256;            // 0..1023
            int row = sl >> 3, g = sl & 7;     // row 0..127, float4-granule 0..7
            int r = m0 + row;
            int b = r / KF, np = r - b * KF;
            float4 hv = {0.f, 0.f, 0.f, 0.f};
            if (np <= 512) {
                int d0 = k0 + g * 4;
                float4 s4 = *(const float4*)(ls + d0);
                float4 b4 = *(const float4*)(lb + d0);
                int i1 = b * NTOK + np;
                float2 st1 = stats[i1];
                float4 va = *(const float4*)(tt + (size_t)i1 * 256 + d0);
                float hax = (va.x - st1.x) * st1.y * s4.x + b4.x;
                float hay = (va.y - st1.x) * st1.y * s4.y + b4.y;
                float haz = (va.z - st1.x) * st1.y * s4.z + b4.z;
                float haw = (va.w - st1.x) * st1.y * s4.w + b4.w;
                float hbx = 0.f, hby = 0.f, hbz = 0.f, hbw = 0.f;
                if (np >= 1) {
                    int i2 = b * NTOK + (NTOK - np);
                    float2 st2 = stats[i2];
                    float4 vb = *(const float4*)(tt + (size_t)i2 * 256 + d0);
                    hbx = (vb.x - st2.x) * st2.y * s4.x + b4.x;
                    hby = (vb.y - st2.x) * st2.y * s4.y + b4.y;
                    hbz = (vb.z - st2.x) * st2.y * s4.z + b4.z;
                    hbw = (vb.w - st2.x) * st2.y * s4.w + b4.w;
                }
                if (zz) { hv.x = hax - hbx; hv.y = hay - hby; hv.z = haz - hbz; hv.w = haw - hbw; }
                else    { hv.x = hax + hbx; hv.y = hay + hby; hv.z = haz + hbz; hv.w = haw + hbw; }
            }
            ushort4 oh, ol;
            split_bf16(hv.x, oh.x, ol.x); split_bf16(hv.y, oh.y, ol.y);
            split_bf16(hv.z, oh.z, ol.z); split_bf16(hv.w, oh.w, ol.w);
            int addr = (row * 4 + ((g >> 1) ^ ((row >> 1) & 3))) * 8 + (g & 1) * 4;
            *(ushort4*)(sAh + addr) = oh;
            *(ushort4*)(sAl + addr) = ol;
        }
        a_stage144x32(sBh, Bh + k0, 256, tid);
        a_stage144x32(sBl, Bl + k0, 256, tid);
        __syncthreads();
        int q = lane >> 4;
        short8 ah[2], al[2];
#pragma unroll
        for (int i = 0; i < 2; i++) {
            int r = wr + i * 16 + (lane & 15);
            ah[i] = ld8x32(sAh, r, q); al[i] = ld8x32(sAl, r, q);
        }
#pragma unroll
        for (int j = 0; j < 9; j++) {
            int rb = j * 16 + (lane & 15);
            short8 bh = ld8x32(sBh, rb, q), bl = ld8x32(sBl, rb, q);
#pragma unroll
            for (int i = 0; i < 2; i++) {
                MFMA16(acc[i][j], ah[i], bh);
                MFMA16(acc[i][j], ah[i], bl);
                MFMA16(acc[i][j], al[i], bh);
            }
        }
        __syncthreads();
    }
    int q4 = (lane >> 4) * 4;
#pragma unroll
    for (int i = 0; i < 2; i++) {
        int r = m0 + wr + i * 16 + q4;
        int bidx = r / KF, kp = r - bidx * KF;
#pragma unroll
        for (int j = 0; j < 9; j++) {
            int c = j * 16 + (lane & 15);
            ushort4 oh, ol;
            split_bf16(acc[i][j][0], oh.x, ol.x);
            split_bf16(acc[i][j][1], oh.y, ol.y);
            split_bf16(acc[i][j][2], oh.z, ol.z);
            split_bf16(acc[i][j][3], oh.w, ol.w);
            size_t off = ((size_t)bidx * MF + c) * KF + kp;
            *(ushort4*)(Oh + off) = oh;
            *(ushort4*)(Ol + off) = ol;
        }
    }
}

// ---------------------------------------------------------------------------
// Dual split GEMM + butterfly. A: C1/S1 [640][576]; B: Yc/Ys flat [9216][576].
// 512 threads (8 waves), tile 128(k-rows) x 64(flat cols), BK=32, grid(5,144).
// LDS 48KB -> 3 blk/CU = 24 waves/CU. Wave (w>>1)->k-quad, (w&1)->col-quad.
__global__ __launch_bounds__(512, 6) void fft_big_dual(
    const unsigned short* __restrict__ C1h, const unsigned short* __restrict__ C1l,
    const unsigned short* __restrict__ S1h, const unsigned short* __restrict__ S1l,
    const unsigned short* __restrict__ Ych, const unsigned short* __restrict__ Ycl,
    const unsigned short* __restrict__ Ysh, const unsigned short* __restrict__ Ysl,
    float* __restrict__ t) {
    __shared__ __align__(16) unsigned short sC1h[4096], sC1l[4096], sS1h[4096], sS1l[4096];
    __shared__ __align__(16) unsigned short sYch[2048], sYcl[2048], sYsh[2048], sYsl[2048];
    int k0m = blockIdx.x * 128, n0 = blockIdx.y * 64;
    int tid = threadIdx.x, lane = tid & 63, w = tid >> 6;
    int wr = (w >> 1) * 32, wc = (w & 1) * 32;
    f32x4 z = {0.f, 0.f, 0.f, 0.f};
    f32x4 U[2][2], V[2][2];
#pragma unroll
    for (int i = 0; i < 2; i++)
#pragma unroll
        for (int j = 0; j < 2; j++) { U[i][j] = z; V[i][j] = z; }
    for (int kk0 = 0; kk0 < KF; kk0 += 32) {
        // A: 4 matrices 128x32, one slot per thread each
        {
            int row = tid >> 2, gc = (tid & 3) ^ ((row >> 1) & 3);
            size_t ga = (size_t)k0m * KF + kk0 + (size_t)row * KF + gc * 8;
            unsigned short* lbase0 = sC1h + (size_t)(w * 64) * 8;
            unsigned short* lbase1 = sC1l + (size_t)(w * 64) * 8;
            unsigned short* lbase2 = sS1h + (size_t)(w * 64) * 8;
            unsigned short* lbase3 = sS1l + (size_t)(w * 64) * 8;
            gl2lds16(C1h + ga, lbase0);
            gl2lds16(C1l + ga, lbase1);
            gl2lds16(S1h + ga, lbase2);
            gl2lds16(S1l + ga, lbase3);
        }
        // Y: matrix chosen by w>>1, half by w&1 (each 2 calls of 64 slots)
        {
            int m = w >> 1, p = w & 1;
            const unsigned short* yg;
            unsigned short* yl;
            if (m == 0)      { yg = Ych; yl = sYch; }
            else if (m == 1) { yg = Ycl; yl = sYcl; }
            else if (m == 2) { yg = Ysh; yl = sYsh; }
            else             { yg = Ysl; yl = sYsl; }
            size_t gb = (size_t)n0 * KF + kk0;
#pragma unroll
            for (int s = 0; s < 2; s++) {
                int slot = p * 128 + s * 64;
                int sl = slot + lane;
                int row = sl >> 2, gc = (sl & 3) ^ ((row >> 1) & 3);
                gl2lds16(yg + gb + (size_t)row * KF + gc * 8, yl + slot * 8);
            }
        }
        __syncthreads();
        int q = lane >> 4;
        short8 bch[2], bcl[2], bsh[2], bsl[2];
#pragma unroll
        for (int j = 0; j < 2; j++) {
            int r2 = wc + j * 16 + (lane & 15);
            bch[j] = ld8x32(sYch, r2, q); bcl[j] = ld8x32(sYcl, r2, q);
            bsh[j] = ld8x32(sYsh, r2, q); bsl[j] = ld8x32(sYsl, r2, q);
        }
#pragma unroll
        for (int i = 0; i < 2; i++) {
            int r1 = wr + i * 16 + (lane & 15);
            short8 ach = ld8x32(sC1h, r1, q), acl = ld8x32(sC1l, r1, q);
            short8 ash = ld8x32(sS1h, r1, q), asl = ld8x32(sS1l, r1, q);
#pragma unroll
            for (int j = 0; j < 2; j++) {
                MFMA16(U[i][j], ach, bch[j]);
                MFMA16(U[i][j], ach, bcl[j]);
                MFMA16(U[i][j], acl, bch[j]);
                MFMA16(V[i][j], ash, bsh[j]);
                MFMA16(V[i][j], ash, bsl[j]);
                MFMA16(V[i][j], asl, bsh[j]);
            }
        }
        __syncthreads();
    }
    int q4 = (lane >> 4) * 4;
#pragma unroll
    for (int j = 0; j < 2; j++) {
        int rcol = n0 + wc + j * 16 + (lane & 15);
        int b = rcol / MF, mm = rcol - b * MF;
        float* tb = t + (size_t)b * NTOK * DIM;
        if (mm > 128) continue;
#pragma unroll
        for (int i = 0; i < 2; i++) {
            int kk = k0m + wr + i * 16 + q4;
#pragma unroll
            for (int g = 0; g < 4; g++) {
                int k = kk + g;
                if (k > 512) continue;
                float u = U[i][j][g], v = V[i][j][g];
                tb[(size_t)k * 256 + mm] += u - v;
                if (mm >= 1 && mm <= 127) tb[(size_t)k * 256 + 256 - mm] += u + v;
                if (k >= 1) {
                    tb[(size_t)(NTOK - k) * 256 + mm] += u + v;
                    if (mm >= 1 && mm <= 127) tb[(size_t)(NTOK - k) * 256 + 256 - mm] += u - v;
                }
            }
        }
    }
}

// ---------------------------------------------------------------------------
// Fused FFN v4b: t += leaky(hh @ w1 + b1) @ w2 + b2.  M-tile 256, 512 threads,
// grid 257 (2 dispatch rounds). H-chunk 64 (16 chunks).
// LDS: 3 rotating 32KB weight buffers + sH 32KB ([256][64]) = 128KB -> 1 blk/CU
// (uniform lockstep progress keeps weight reads L2-hot; round-3 regime).
// GEMM1: 8 waves x (32 rows x 64 cols), A in regs. GEMM2: 8 waves x (64 x 128)
// -> ratio 2.67 MFMA:ds_read; B-frags loaded in 2 groups of 4 to cap VGPR peak.
// Accumulation h-order identical to v1-v3 -> bit-identical output.
__global__ __launch_bounds__(512, 2) void gemm_ffn_fused(
    const unsigned short* __restrict__ A, const unsigned short* __restrict__ W1t,
    const float* __restrict__ b1, const unsigned short* __restrict__ W2t,
    const float* __restrict__ b2, float* __restrict__ t) {
    __shared__ __align__(16) unsigned short sBuf[3][16384];  // 3 x 32 KB
    __shared__ __align__(16) unsigned short sH[16384];       // 32 KB: [256][64]
    int m0 = blockIdx.x * 256;
    int tid = threadIdx.x, lane = tid & 63, w = tid >> 6;
    // GEMM1 wave layout: 8 waves over 256x64 -> 32 rows x 64 cols each
    int wr1 = w * 32;
    // GEMM2 wave layout: 8 waves over 256x256 -> 64 rows x 128 cols each
    int wr2 = (w & 3) * 64, wc2 = (w >> 2) * 128;
    // w1 panel stage coords: 512 slots (64 rows x 8 granules), 1 slot/thread/panel
    int prow = tid >> 3, pgc = (tid & 7) ^ (prow & 7);
    // A rows for GEMM1 into registers (clamped for M-tail; epilogue guards)
    short8 areg[2][8];
#pragma unroll
    for (int i = 0; i < 2; i++) {
        int rr = m0 + wr1 + i * 16 + (lane & 15);
        if (rr > MROWS - 1) rr = MROWS - 1;
        const unsigned short* ap = A + (size_t)rr * 256 + (lane >> 4) * 8;
#pragma unroll
        for (int p = 0; p < 4; p++)
#pragma unroll
            for (int kc = 0; kc < 2; kc++)
                areg[i][p * 2 + kc] = *(const short8*)(ap + p * 64 + kc * 32);
    }
    f32x4 z = {0.f, 0.f, 0.f, 0.f};
    f32x4 acc2[4][8];
#pragma unroll
    for (int i = 0; i < 4; i++)
#pragma unroll
        for (int j = 0; j < 8; j++) acc2[i][j] = z;
    int q4 = (lane >> 4) * 4;
    unsigned short* bw1 = sBuf[0];
    unsigned short* bw2 = sBuf[1];
    unsigned short* bfr = sBuf[2];
    // prologue: stage w1(0), w2(0)
#pragma unroll
    for (int p = 0; p < 4; p++)
        gl2lds16(W1t + (size_t)prow * 256 + p * 64 + pgc * 8, bw1 + p * 4096 + (w * 64) * 8);
#pragma unroll
    for (int rb = 0; rb < 2; rb++)
        a_stage128_512(bw2 + rb * 8192, W2t + (size_t)(rb * 128) * 1024, 1024, tid, 127);
    for (int hc = 0; hc < 16; hc++) {
        int h0 = hc * 64;
        __syncthreads();   // BarX: w1(hc) in bw1, w2(hc) in bw2 ready; bfr free
        // issue w1(hc+1) -> bfr (hidden under GEMM1)
        if (hc < 15) {
            const unsigned short* wsrc = W1t + (size_t)(h0 + 64 + prow) * 256;
#pragma unroll
            for (int p = 0; p < 4; p++)
                gl2lds16(wsrc + p * 64 + pgc * 8, bfr + p * 4096 + (w * 64) * 8);
        }
        // GEMM1: acc1 = A(regs) x w1-chunk (all 64 H-cols per wave) from bw1
        f32x4 acc1[2][4] = {{z, z, z, z}, {z, z, z, z}};
#pragma unroll
        for (int p = 0; p < 4; p++)
#pragma unroll
            for (int kc = 0; kc < 2; kc++) {
                int q = (lane >> 4) + kc * 4;
                short8 bh[4];
#pragma unroll
                for (int j = 0; j < 4; j++)
                    bh[j] = ld8x64(bw1 + p * 4096, j * 16 + (lane & 15), q);
#pragma unroll
                for (int i = 0; i < 2; i++)
#pragma unroll
                    for (int j = 0; j < 4; j++) MFMA16(acc1[i][j], areg[i][p * 2 + kc], bh[j]);
            }
        // bias + leaky + bf16 -> sH
#pragma unroll
        for (int j = 0; j < 4; j++) {
            int col = j * 16 + (lane & 15);
            float bv = b1[h0 + col];
#pragma unroll
            for (int i = 0; i < 2; i++)
#pragma unroll
                for (int g = 0; g < 4; g++) {
                    int row = wr1 + i * 16 + q4 + g;
                    float val = acc1[i][j][g] + bv;
                    val = val > 0.f ? val : 0.01f * val;
                    sH[(row * 8 + ((col >> 3) ^ (row & 7))) * 8 + (col & 7)] = rne_bf16(val);
                }
        }
        __syncthreads();   // BarY: sH ready; w1(hc+1) drained into bfr
        // issue w2(hc+1) -> bw1 (GEMM1 done with it; hidden under GEMM2)
        if (hc < 15) {
#pragma unroll
            for (int rb = 0; rb < 2; rb++)
                a_stage128_512(bw1 + rb * 8192, W2t + (size_t)(rb * 128) * 1024 + h0 + 64, 1024, tid, 127);
        }
        // GEMM2: acc2 += sH x w2-chunk from bw2 (64 rows x 128 cols per wave)
        // B-frags in 2 groups of 4 to cap live-register peak.
#pragma unroll
        for (int kc = 0; kc < 2; kc++) {
            int q = (lane >> 4) + kc * 4;
            short8 ah[4];
#pragma unroll
            for (int i = 0; i < 4; i++)
                ah[i] = ld8x64(sH, wr2 + i * 16 + (lane & 15), q);
#pragma unroll
            for (int jj = 0; jj < 2; jj++) {
                short8 bh[4];
#pragma unroll
                for (int j = 0; j < 4; j++) {
                    int n = wc2 + (jj * 4 + j) * 16 + (lane & 15);
                    bh[j] = ld8x64(bw2 + (n >> 7) * 8192, n & 127, q);
                }
#pragma unroll
                for (int i = 0; i < 4; i++)
#pragma unroll
                    for (int j = 0; j < 4; j++) MFMA16(acc2[i][jj * 4 + j], ah[i], bh[j]);
            }
        }
        // rotate: next w1 = bfr, next w2 = old bw1 (w2(hc+1)), free = old bw2
        unsigned short* t0 = bw1;
        bw1 = bfr; bfr = bw2; bw2 = t0;
    }
#pragma unroll
    for (int i = 0; i < 4; i++) {
        int r = m0 + wr2 + i * 16 + q4;
#pragma unroll
        for (int j = 0; j < 8; j++) {
            int c = wc2 + j * 16 + (lane & 15);
            float bv = b2[c];
#pragma unroll
            for (int g = 0; g < 4; g++) {
                int rr = r + g;
                if (rr < MROWS) t[(size_t)rr * 256 + c] += acc2[i][j][g] + bv;
            }
        }
    }
}

// ---------------------------------------------------------------------------
__global__ __launch_bounds__(256) void head_kernel(const float* __restrict__ t,
                                                   const float* __restrict__ hs, const float* __restrict__ hb,
                                                   const float* __restrict__ hw, const float* __restrict__ hbias,
                                                   float* __restrict__ out) {
    __shared__ float red[256];
    __shared__ float lnv[256];
    int b = blockIdx.x, tid = threadIdx.x;
    const float* tb = t + (size_t)b * NTOK * DIM;
    float s = 0.f;
    for (int m = 0; m < NTOK; m++) s += tb[m * DIM + tid];
    s *= (1.f / 1025.f);
    red[tid] = s;
    __syncthreads();
    for (int off = 128; off; off >>= 1) {
        if (tid < off) red[tid] += red[tid + off];
        __syncthreads();
    }
    float mean = red[0] * (1.f / 256.f);
    __syncthreads();
    float d = s - mean;
    red[tid] = d * d;
    __syncthreads();
    for (int off = 128; off; off >>= 1) {
        if (tid < off) red[tid] += red[tid + off];
        __syncthreads();
    }
    float rstd = rsqrtf(red[0] * (1.f / 256.f) + LN_EPS);
    __syncthreads();
    lnv[tid] = d * rstd * hs[tid] + hb[tid];
    __syncthreads();
    float lo[4];
#pragma unroll
    for (int jj = 0; jj < 4; jj++) {
        int n = tid + jj * 256;
        float a = -1e30f;
        if (n < NCLS) {
            a = hbias[n];
            for (int dd = 0; dd < DIM; dd++) a += lnv[dd] * hw[dd * NCLS + n];
        }
        lo[jj] = a;
    }
    float mx = fmaxf(fmaxf(lo[0], lo[1]), fmaxf(lo[2], lo[3]));
    red[tid] = mx;
    __syncthreads();
    for (int off = 128; off; off >>= 1) {
        if (tid < off) red[tid] = fmaxf(red[tid], red[tid + off]);
        __syncthreads();
    }
    float gmax = red[0];
    __syncthreads();
    float ev[4];
    float es = 0.f;
#pragma unroll
    for (int jj = 0; jj < 4; jj++) {
        int n = tid + jj * 256;
        ev[jj] = 0.f;
        if (n < NCLS) {
            ev[jj] = expf(lo[jj] - gmax);
            es += ev[jj];
        }
    }
    red[tid] = es;
    __syncthreads();
    for (int off = 128; off; off >>= 1) {
        if (tid < off) red[tid] += red[tid + off];
        __syncthreads();
    }
    float inv = 1.f / red[0];
#pragma unroll
    for (int jj = 0; jj < 4; jj++) {
        int n = tid + jj * 256;
        if (n < NCLS) out[(size_t)b * NCLS + n] = ev[jj] * inv;
    }
}

// ---------------------------------------------------------------------------
extern "C" void kernel_launch(void* const* d_in, const int* in_sizes, int n_in,
                              void* d_out, int out_size, void* d_ws, size_t ws_size,
                              hipStream_t stream) {
    const float* x      = (const float*)d_in[0];
    const float* conv_w = (const float*)d_in[1];
    const float* conv_b = (const float*)d_in[2];
    const float* pos    = (const float*)d_in[3];
    const float* cls    = (const float*)d_in[4];
    const float* ln1_s  = (const float*)d_in[5];
    const float* ln1_b  = (const float*)d_in[6];
    const float* ln2_s  = (const float*)d_in[7];
    const float* ln2_b  = (const float*)d_in[8];
    const float* w1     = (const float*)d_in[9];
    const float* b1     = (const float*)d_in[10];
    const float* w2     = (const float*)d_in[11];
    const float* b2     = (const float*)d_in[12];
    const float* hls    = (const float*)d_in[13];
    const float* hlb    = (const float*)d_in[14];
    const float* hw     = (const float*)d_in[15];
    const float* hbias  = (const float*)d_in[16];
    float* out = (float*)d_out;
    char* W = (char*)d_ws;

    // layout (bytes), pool time-multiplexed:
    //   t:    [0, 67,174,400)
    //   pool @ 67,174,400 (167,936,000):
    //     Yct @ +75,497,472 (4 x 10,616,832)      — phase A  (ends +117,964,800)
    //     hh  @ +134,348,800 (33,587,200)         — phase B
    //   C1 grp @ 235,110,400 (4 x 737,280 = 640x576x2)
    //   C2 grp @ 238,059,520 (4 x 131,072)
    //   w1t @ 238,583,808 | w2t @ 241,729,536 | wph @ 244,875,264 | wpl @ 245,268,480
    //   stats @ 245,661,696 (65600 x 8B = 524,800)
    float*          t    = (float*)(W + 0ULL);
    char*           pool = W + 67174400ULL;
    unsigned short* Ycth = (unsigned short*)(pool + 75497472ULL);
    unsigned short* Yctl = (unsigned short*)(pool + 75497472ULL + 10616832ULL);
    unsigned short* Ysth = (unsigned short*)(pool + 75497472ULL + 2 * 10616832ULL);
    unsigned short* Ystl = (unsigned short*)(pool + 75497472ULL + 3 * 10616832ULL);
    unsigned short* hh   = (unsigned short*)(pool + 134348800ULL);
    unsigned short* C1h  = (unsigned short*)(W + 235110400ULL);
    unsigned short* C1l  = (unsigned short*)(W + 235110400ULL + 737280ULL);
    unsigned short* S1h  = (unsigned short*)(W + 235110400ULL + 2 * 737280ULL);
    unsigned short* S1l  = (unsigned short*)(W + 235110400ULL + 3 * 737280ULL);
    unsigned short* C2h  = (unsigned short*)(W + 238059520ULL);
    unsigned short* C2l  = (unsigned short*)(W + 238059520ULL + 131072ULL);
    unsigned short* S2h  = (unsigned short*)(W + 238059520ULL + 2 * 131072ULL);
    unsigned short* S2l  = (unsigned short*)(W + 238059520ULL + 3 * 131072ULL);
    unsigned short* w1t  = (unsigned short*)(W + 238583808ULL);
    unsigned short* w2t  = (unsigned short*)(W + 241729536ULL);
    unsigned short* wph  = (unsigned short*)(W + 244875264ULL);
    unsigned short* wpl  = (unsigned short*)(W + 245268480ULL);
    float2*         stats = (float2*)(W + 245661696ULL);

    gen_dft2<<<dim3(1440), dim3(256), 0, stream>>>(C1h, C1l, S1h, S1l, C2h, C2l, S2h, S2l);
    conv_wp<<<dim3(768), dim3(256), 0, stream>>>(conv_w, wph, wpl);
    conv_w1t<<<dim3(6144), dim3(256), 0, stream>>>(w1, w1t);
    conv_w2t<<<dim3(6144), dim3(256), 0, stream>>>(w2, w2t);
    cls_init<<<dim3(BATCH), dim3(256), 0, stream>>>(cls, pos, t);
    patch_fused<<<dim3(512, 2), dim3(256), 0, stream>>>(x, wph, wpl, conv_b, pos, t);

    for (int l = 0; l < NLAYER; l++) {
        ln_stats<<<dim3(16400), dim3(256), 0, stream>>>(t, stats);
        fold_gemm<<<dim3(288, 2), dim3(256), 0, stream>>>(
            t, stats, ln1_s + l * DIM, ln1_b + l * DIM,
            C2h, C2l, S2h, S2l, Ycth, Yctl, Ysth, Ystl);
        fft_big_dual<<<dim3(5, 144), dim3(512), 0, stream>>>(
            C1h, C1l, S1h, S1l, Ycth, Yctl, Ysth, Ystl, t);
        ln2_bf16<<<dim3(16400), dim3(256), 0, stream>>>(t, hh, ln2_s + l * DIM, ln2_b + l * DIM);
        gemm_ffn_fused<<<dim3(257), dim3(512), 0, stream>>>(
            hh, w1t + (size_t)l * 262144, b1 + (size_t)l * HID,
            w2t + (size_t)l * 262144, b2 + (size_t)l * DIM, t);
    }
    head_kernel<<<dim3(BATCH), dim3(256), 0, stream>>>(t, hls, hlb, hw, hbias, out);
}

// Round 7
// 2442.046 us; speedup vs baseline: 1.4902x; 1.4902x over previous
//
#include <hip/hip_runtime.h>
#include <math.h>

#define BATCH 64
#define CIN 3
#define IMH 512
#define IMW 512
#define PSZ 16
#define DIM 256
#define GHN 32
#define GWN 32
#define NTOK 1025
#define HID 1024
#define NLAYER 6
#define NCLS 1000
#define LN_EPS 1e-5f

// folded dims: token-fold 513 -> pad 576 ; dim-fold 129 -> pad 144
#define KF 576
#define KR 640           // A rows padded for 128-row tiles (5 x 128)
#define MF 144
#define MROWS 65600      // 64*1025

typedef __attribute__((ext_vector_type(8))) short short8;
typedef __attribute__((ext_vector_type(4))) float f32x4;

#define MFMA16(acc, a, b) acc = __builtin_amdgcn_mfma_f32_16x16x32_bf16(a, b, acc, 0, 0, 0)

// ---------------------------------------------------------------------------
__device__ inline unsigned short rne_bf16(float x) {
    unsigned u = __float_as_uint(x);
    return (unsigned short)((u + 0x7FFF + ((u >> 16) & 1)) >> 16);
}
__device__ inline void split_bf16(float x, unsigned short& hi, unsigned short& lo) {
    unsigned short h = rne_bf16(x);
    hi = h;
    float hf = __uint_as_float((unsigned)h << 16);
    lo = rne_bf16(x - hf);
}
__device__ inline float wave_sum(float v) {
#pragma unroll
    for (int off = 32; off; off >>= 1) v += __shfl_xor(v, off);
    return v;
}
// 64-wide tiles (8 granules/row): perm = g ^ (row&7)  -> 2-way banks (free)
__device__ inline short8 ld8x64(const unsigned short* lds, int row, int q) {
    return *(const short8*)(lds + (row * 8 + (q ^ (row & 7))) * 8);
}
// 32-wide tiles (4 granules/row): perm = g ^ ((row>>1)&3) -> 2-way banks (free)
__device__ inline short8 ld8x32(const unsigned short* lds, int row, int q) {
    return *(const short8*)(lds + (row * 4 + (q ^ ((row >> 1) & 3))) * 8);
}
// async global->LDS 16B (lds arg wave-uniform; HW adds lane*16)
__device__ inline void gl2lds16(const unsigned short* g, unsigned short* l) {
    __builtin_amdgcn_global_load_lds((const __attribute__((address_space(1))) unsigned int*)g,
                                     (__attribute__((address_space(3))) unsigned int*)l, 16, 0, 0);
}
// stage 128 rows x 64 bf16 (mask-7 swizzle); row clamped for M-tail (256 thr)
__device__ inline void a_stage128(unsigned short* lds, const unsigned short* g, int lda, int tid, int maxrow) {
    int lane = tid & 63, w = tid >> 6;
#pragma unroll
    for (int s = 0; s < 4; s++) {
        int slot = w * 256 + s * 64;
        int sl = slot + lane;
        int row = sl >> 3, gc = (sl & 7) ^ (row & 7);
        if (row > maxrow) row = maxrow;
        gl2lds16(g + (size_t)row * lda + gc * 8, lds + slot * 8);
    }
}
// stage 128 rows x 64 bf16, 512-thread variant (2 slots/thread)
__device__ inline void a_stage128_512(unsigned short* lds, const unsigned short* g, int lda, int tid, int maxrow) {
    int lane = tid & 63, w = tid >> 6;
#pragma unroll
    for (int s = 0; s < 2; s++) {
        int slot = w * 128 + s * 64;
        int sl = slot + lane;
        int row = sl >> 3, gc = (sl & 7) ^ (row & 7);
        if (row > maxrow) row = maxrow;
        gl2lds16(g + (size_t)row * lda + gc * 8, lds + slot * 8);
    }
}
// stage 128 rows x 32 bf16 (512 slots, 256 thr x 2)
__device__ inline void b_stage128x32(unsigned short* lds, const unsigned short* g, int lda, int tid) {
    int lane = tid & 63;
#pragma unroll
    for (int s = 0; s < 2; s++) {
        int slot = s * 256 + (tid >> 6) * 64;
        int sl = slot + lane;
        int row = sl >> 2, gc = (sl & 3) ^ ((row >> 1) & 3);
        gl2lds16(g + (size_t)row * lda + gc * 8, lds + slot * 8);
    }
}
// stage 144 rows x 32 bf16 (576 slots: 2 full passes + wave0 partial, 256 thr)
__device__ inline void a_stage144x32(unsigned short* lds, const unsigned short* g, int lda, int tid) {
    int lane = tid & 63, w = tid >> 6;
#pragma unroll
    for (int s = 0; s < 2; s++) {
        int slot = s * 256 + w * 64;
        int sl = slot + lane;
        int row = sl >> 2, gc = (sl & 3) ^ ((row >> 1) & 3);
        gl2lds16(g + (size_t)row * lda + gc * 8, lds + slot * 8);
    }
    if (w == 0) {
        int slot = 512;
        int sl = slot + lane;
        int row = sl >> 2, gc = (sl & 3) ^ ((row >> 1) & 3);
        gl2lds16(g + (size_t)row * lda + gc * 8, lds + slot * 8);
    }
}

// ---------------------------------------------------------------------------
// DFT matrices bf16 hi/lo. C1/S1: [640][576] zero-padded past 512 (rows & cols).
__global__ __launch_bounds__(256) void gen_dft2(unsigned short* C1h, unsigned short* C1l,
                                                unsigned short* S1h, unsigned short* S1l,
                                                unsigned short* C2h, unsigned short* C2l,
                                                unsigned short* S2h, unsigned short* S2l) {
    int idx = blockIdx.x * 256 + threadIdx.x;
    if (idx < KR * KF) {
        int k = idx / KF, n = idx - k * KF;
        float c = 0.f, s = 0.f;
        if (k <= 512 && n <= 512) {
            int r = (k * n) % 1025;
            double ang = 6.283185307179586476925287 * (double)r / 1025.0;
            c = (float)cos(ang); s = (float)sin(ang);
        }
        unsigned short h, l;
        split_bf16(c, h, l); C1h[idx] = h; C1l[idx] = l;
        split_bf16(s, h, l); S1h[idx] = h; S1l[idx] = l;
    }
    if (idx < 256 * 256) {
        int k = idx >> 8, n = idx & 255;
        int r = (k * n) & 255;
        double ang = 6.283185307179586476925287 * (double)r / 256.0;
        float c = (float)cos(ang), s = (float)sin(ang);
        unsigned short h, l;
        split_bf16(c, h, l); C2h[idx] = h; C2l[idx] = l;
        split_bf16(s, h, l); S2h[idx] = h; S2l[idx] = l;
    }
}

// wp hi/lo: conv_w already [d=256][k=768], k = c*256+p*16+q
__global__ __launch_bounds__(256) void conv_wp(const float* __restrict__ w,
                                               unsigned short* __restrict__ wph, unsigned short* __restrict__ wpl) {
    int idx = blockIdx.x * 256 + threadIdx.x;
    unsigned short h, l;
    split_bf16(w[idx], h, l);
    wph[idx] = h; wpl[idx] = l;
}
__global__ __launch_bounds__(256) void conv_w1t(const float* __restrict__ w1, unsigned short* __restrict__ w1t) {
    int idx = blockIdx.x * 256 + threadIdx.x;
    int l = idx / 262144, rem = idx - l * 262144;
    int n = rem >> 8, k = rem & 255;
    w1t[idx] = rne_bf16(w1[(size_t)l * 262144 + (size_t)k * 1024 + n]);
}
__global__ __launch_bounds__(256) void conv_w2t(const float* __restrict__ w2, unsigned short* __restrict__ w2t) {
    int idx = blockIdx.x * 256 + threadIdx.x;
    int l = idx / 262144, rem = idx - l * 262144;
    int n = rem >> 10, k = rem & 1023;
    w2t[idx] = rne_bf16(w2[(size_t)l * 262144 + (size_t)k * 256 + n]);
}

// ---------------------------------------------------------------------------
__global__ __launch_bounds__(256) void cls_init(const float* __restrict__ cls, const float* __restrict__ pos,
                                                float* __restrict__ t) {
    int b = blockIdx.x, tid = threadIdx.x;
    t[(size_t)b * NTOK * DIM + tid] = cls[tid] + pos[tid];
}

// ---------------------------------------------------------------------------
// Fused patch embed: reads x directly, splits hi/lo in-register, 3-pass MFMA.
// M=65536 patches, N=256 dims, K=768. 128x128 tile, BK=32 (32 KB LDS -> 4 blk/CU),
// grid(512,2).
__global__ __launch_bounds__(256) void patch_fused(const float* __restrict__ x,
                                                   const unsigned short* __restrict__ wph,
                                                   const unsigned short* __restrict__ wpl,
                                                   const float* __restrict__ cb, const float* __restrict__ pos,
                                                   float* __restrict__ t) {
    __shared__ __align__(16) unsigned short sAh[4096], sAl[4096], sBh[4096], sBl[4096];
    int m0 = blockIdx.x * 128, n0 = blockIdx.y * 128;
    int tid = threadIdx.x, lane = tid & 63, w = tid >> 6;
    int wr = (w >> 1) * 64, wc = (w & 1) * 64;
    f32x4 z = {0.f, 0.f, 0.f, 0.f};
    f32x4 acc[4][4] = {{z, z, z, z}, {z, z, z, z}, {z, z, z, z}, {z, z, z, z}};
    for (int k0 = 0; k0 < 768; k0 += 32) {
        // A tile: 128 rows x 32 k floats = 1024 float4, 4/thread
#pragma unroll
        for (int s = 0; s < 4; s++) {
            int lin = s * 1024 + tid * 4;
            int row = lin >> 5, kc = lin & 31;
            int m = m0 + row;
            int bb = m >> 10, gh = (m >> 5) & 31, gw = m & 31;
            int k = k0 + kc;
            int c = k >> 8, pp = (k >> 4) & 15, q = k & 15;
            const float* gp = x + (size_t)bb * 786432 + c * 262144 + gh * 8192 + pp * 512 + gw * 16 + q;
            float4 v = *(const float4*)gp;
            ushort4 oh, ol;
            split_bf16(v.x, oh.x, ol.x); split_bf16(v.y, oh.y, ol.y);
            split_bf16(v.z, oh.z, ol.z); split_bf16(v.w, oh.w, ol.w);
            int g = kc >> 3, half = (kc >> 2) & 1;
            int addr = (row * 4 + (g ^ ((row >> 1) & 3))) * 8 + half * 4;
            *(ushort4*)(sAh + addr) = oh;
            *(ushort4*)(sAl + addr) = ol;
        }
        b_stage128x32(sBh, wph + (size_t)n0 * 768 + k0, 768, tid);
        b_stage128x32(sBl, wpl + (size_t)n0 * 768 + k0, 768, tid);
        __syncthreads();
        int q = lane >> 4;
        short8 ah[4], al[4], bh8[4], bl8[4];
#pragma unroll
        for (int i = 0; i < 4; i++) {
            ah[i] = ld8x32(sAh, wr + i * 16 + (lane & 15), q);
            al[i] = ld8x32(sAl, wr + i * 16 + (lane & 15), q);
            bh8[i] = ld8x32(sBh, wc + i * 16 + (lane & 15), q);
            bl8[i] = ld8x32(sBl, wc + i * 16 + (lane & 15), q);
        }
#pragma unroll
        for (int i = 0; i < 4; i++)
#pragma unroll
            for (int j = 0; j < 4; j++) {
                MFMA16(acc[i][j], ah[i], bh8[j]);
                MFMA16(acc[i][j], ah[i], bl8[j]);
                MFMA16(acc[i][j], al[i], bh8[j]);
            }
        __syncthreads();
    }
    int q4 = (lane >> 4) * 4;
#pragma unroll
    for (int i = 0; i < 4; i++) {
        int r = m0 + wr + i * 16 + q4;
#pragma unroll
        for (int j = 0; j < 4; j++) {
            int c = n0 + wc + j * 16 + (lane & 15);
#pragma unroll
            for (int g = 0; g < 4; g++) {
                int rr = r + g;
                int bb = rr >> 10, tok = 1 + (rr & 1023);
                t[((size_t)bb * NTOK + tok) * 256 + c] =
                    acc[i][j][g] + cb[c] + pos[(size_t)tok * 256 + c];
            }
        }
    }
}

// ---------------------------------------------------------------------------
// Per-token LN stats: stats[m] = (mean, rstd). One wave per token.
__global__ __launch_bounds__(256) void ln_stats(const float* __restrict__ t, float2* __restrict__ stats) {
    int wave = threadIdx.x >> 6, lane = threadIdx.x & 63;
    int m = blockIdx.x * 4 + wave;   // < 65600 exact
    const float* row = t + (size_t)m * DIM;
    float4 v = *(const float4*)(row + lane * 4);
    float mean = wave_sum(v.x + v.y + v.z + v.w) * (1.f / 256.f);
    float dx = v.x - mean, dy = v.y - mean, dz = v.z - mean, dw = v.w - mean;
    float sq = wave_sum(dx * dx + dy * dy + dz * dz + dw * dw);
    float rstd = rsqrtf(sq * (1.f / 256.f) + LN_EPS);
    if (lane == 0) stats[m] = make_float2(mean, rstd);
}

// ---------------------------------------------------------------------------
__global__ __launch_bounds__(256) void ln2_bf16(const float* __restrict__ t, unsigned short* __restrict__ hh,
                                                const float* __restrict__ s, const float* __restrict__ bb) {
    int wave = threadIdx.x >> 6, lane = threadIdx.x & 63;
    int m = blockIdx.x * 4 + wave;
    const float* row = t + (size_t)m * DIM;
    float4 v = *(const float4*)(row + lane * 4);
    float mean = wave_sum(v.x + v.y + v.z + v.w) * (1.f / 256.f);
    float dx = v.x - mean, dy = v.y - mean, dz = v.z - mean, dw = v.w - mean;
    float sq = wave_sum(dx * dx + dy * dy + dz * dz + dw * dw);
    float rstd = rsqrtf(sq * (1.f / 256.f) + LN_EPS);
    float4 s4 = *(const float4*)(s + lane * 4);
    float4 b4 = *(const float4*)(bb + lane * 4);
    ushort4 o;
    o.x = rne_bf16(dx * rstd * s4.x + b4.x);
    o.y = rne_bf16(dy * rstd * s4.y + b4.y);
    o.z = rne_bf16(dz * rstd * s4.z + b4.z);
    o.w = rne_bf16(dw * rstd * s4.w + b4.w);
    *(ushort4*)(hh + (size_t)m * DIM + lane * 4) = o;
}

// ---------------------------------------------------------------------------
// Fused LN1 + token-fold + split-bf16 GEMM (3-pass).
// A built in-register from t (normalize via stats, fold +/- by z), B = C2/S2 rows [0..143].
// Output transposed+split O[b][c:144][kp:576] hi/lo. Tile 128x144, BK=32, grid(288, 2).
__global__ __launch_bounds__(256) void fold_gemm(
    const float* __restrict__ tt, const float2* __restrict__ stats,
    const float* __restrict__ ls, const float* __restrict__ lb,
    const unsigned short* __restrict__ C2h, const unsigned short* __restrict__ C2l,
    const unsigned short* __restrict__ S2h, const unsigned short* __restrict__ S2l,
    unsigned short* __restrict__ Ycth, unsigned short* __restrict__ Yctl,
    unsigned short* __restrict__ Ysth, unsigned short* __restrict__ Ystl) {
    __shared__ __align__(16) unsigned short sAh[4096], sAl[4096], sBh[4608], sBl[4608];
    int m0 = blockIdx.x * 128;
    int zz = blockIdx.y;
    const unsigned short* Bh = zz ? S2h : C2h;
    const unsigned short* Bl = zz ? S2l : C2l;
    unsigned short* Oh = zz ? Ysth : Ycth;
    unsigned short* Ol = zz ? Ystl : Yctl;
    int tid = threadIdx.x, lane = tid & 63, w = tid >> 6;
    int wr = w * 32;
    f32x4 zf = {0.f, 0.f, 0.f, 0.f};
    f32x4 acc[2][9];
#pragma unroll
    for (int i = 0; i < 2; i++)
#pragma unroll
        for (int j = 0; j < 9; j++) acc[i][j] = zf;
    for (int k0 = 0; k0 < 256; k0 += 32) {
        // A: 128 rows x 32 dims built from t with LN + fold, split hi/lo
#pragma unroll
        for (int s = 0; s < 4; s++) {
            int sl = tid + s * 256;            // 0..1023
            int row = sl >> 3, g = sl & 7;     // row 0..127, float4-granule 0..7
            int r = m0 + row;
            int b = r / KF, np = r - b * KF;
            float4 hv = {0.f, 0.f, 0.f, 0.f};
            if (np <= 512) {
                int d0 = k0 + g * 4;
                float4 s4 = *(const float4*)(ls + d0);
                float4 b4 = *(const float4*)(lb + d0);
                int i1 = b * NTOK + np;
                float2 st1 = stats[i1];
                float4 va = *(const float4*)(tt + (size_t)i1 * 256 + d0);
                float hax = (va.x - st1.x) * st1.y * s4.x + b4.x;
                float hay = (va.y - st1.x) * st1.y * s4.y + b4.y;
                float haz = (va.z - st1.x) * st1.y * s4.z + b4.z;
                float haw = (va.w - st1.x) * st1.y * s4.w + b4.w;
                float hbx = 0.f, hby = 0.f, hbz = 0.f, hbw = 0.f;
                if (np >= 1) {
                    int i2 = b * NTOK + (NTOK - np);
                    float2 st2 = stats[i2];
                    float4 vb = *(const float4*)(tt + (size_t)i2 * 256 + d0);
                    hbx = (vb.x - st2.x) * st2.y * s4.x + b4.x;
                    hby = (vb.y - st2.x) * st2.y * s4.y + b4.y;
                    hbz = (vb.z - st2.x) * st2.y * s4.z + b4.z;
                    hbw = (vb.w - st2.x) * st2.y * s4.w + b4.w;
                }
                if (zz) { hv.x = hax - hbx; hv.y = hay - hby; hv.z = haz - hbz; hv.w = haw - hbw; }
                else    { hv.x = hax + hbx; hv.y = hay + hby; hv.z = haz + hbz; hv.w = haw + hbw; }
            }
            ushort4 oh, ol;
            split_bf16(hv.x, oh.x, ol.x); split_bf16(hv.y, oh.y, ol.y);
            split_bf16(hv.z, oh.z, ol.z); split_bf16(hv.w, oh.w, ol.w);
            int addr = (row * 4 + ((g >> 1) ^ ((row >> 1) & 3))) * 8 + (g & 1) * 4;
            *(ushort4*)(sAh + addr) = oh;
            *(ushort4*)(sAl + addr) = ol;
        }
        a_stage144x32(sBh, Bh + k0, 256, tid);
        a_stage144x32(sBl, Bl + k0, 256, tid);
        __syncthreads();
        int q = lane >> 4;
        short8 ah[2], al[2];
#pragma unroll
        for (int i = 0; i < 2; i++) {
            int r = wr + i * 16 + (lane & 15);
            ah[i] = ld8x32(sAh, r, q); al[i] = ld8x32(sAl, r, q);
        }
#pragma unroll
        for (int j = 0; j < 9; j++) {
            int rb = j * 16 + (lane & 15);
            short8 bh = ld8x32(sBh, rb, q), bl = ld8x32(sBl, rb, q);
#pragma unroll
            for (int i = 0; i < 2; i++) {
                MFMA16(acc[i][j], ah[i], bh);
                MFMA16(acc[i][j], ah[i], bl);
                MFMA16(acc[i][j], al[i], bh);
            }
        }
        __syncthreads();
    }
    int q4 = (lane >> 4) * 4;
#pragma unroll
    for (int i = 0; i < 2; i++) {
        int r = m0 + wr + i * 16 + q4;
        int bidx = r / KF, kp = r - bidx * KF;
#pragma unroll
        for (int j = 0; j < 9; j++) {
            int c = j * 16 + (lane & 15);
            ushort4 oh, ol;
            split_bf16(acc[i][j][0], oh.x, ol.x);
            split_bf16(acc[i][j][1], oh.y, ol.y);
            split_bf16(acc[i][j][2], oh.z, ol.z);
            split_bf16(acc[i][j][3], oh.w, ol.w);
            size_t off = ((size_t)bidx * MF + c) * KF + kp;
            *(ushort4*)(Oh + off) = oh;
            *(ushort4*)(Ol + off) = ol;
        }
    }
}

// ---------------------------------------------------------------------------
// Dual split GEMM + butterfly. A: C1/S1 [640][576]; B: Yc/Ys flat [9216][576].
// 512 threads (8 waves), tile 128(k-rows) x 64(flat cols), BK=32, grid(720) 1D.
// XCD-aware swizzle: wg = (bid&7)*90 + (bid>>3) (bijective, 720=8*90) so each
// XCD owns 18 contiguous col-groups -> the 5 k-blocks sharing a Y-slice land on
// ONE XCD's L2 instead of 5 (cuts ~5x Y re-fetch from HBM).
__global__ __launch_bounds__(512, 6) void fft_big_dual(
    const unsigned short* __restrict__ C1h, const unsigned short* __restrict__ C1l,
    const unsigned short* __restrict__ S1h, const unsigned short* __restrict__ S1l,
    const unsigned short* __restrict__ Ych, const unsigned short* __restrict__ Ycl,
    const unsigned short* __restrict__ Ysh, const unsigned short* __restrict__ Ysl,
    float* __restrict__ t) {
    __shared__ __align__(16) unsigned short sC1h[4096], sC1l[4096], sS1h[4096], sS1l[4096];
    __shared__ __align__(16) unsigned short sYch[2048], sYcl[2048], sYsh[2048], sYsl[2048];
    int bid = blockIdx.x;
    int wg = (bid & 7) * 90 + (bid >> 3);
    int k0m = (wg % 5) * 128, n0 = (wg / 5) * 64;
    int tid = threadIdx.x, lane = tid & 63, w = tid >> 6;
    int wr = (w >> 1) * 32, wc = (w & 1) * 32;
    f32x4 z = {0.f, 0.f, 0.f, 0.f};
    f32x4 U[2][2], V[2][2];
#pragma unroll
    for (int i = 0; i < 2; i++)
#pragma unroll
        for (int j = 0; j < 2; j++) { U[i][j] = z; V[i][j] = z; }
    for (int kk0 = 0; kk0 < KF; kk0 += 32) {
        // A: 4 matrices 128x32, one slot per thread each
        {
            int row = tid >> 2, gc = (tid & 3) ^ ((row >> 1) & 3);
            size_t ga = (size_t)k0m * KF + kk0 + (size_t)row * KF + gc * 8;
            unsigned short* lbase0 = sC1h + (size_t)(w * 64) * 8;
            unsigned short* lbase1 = sC1l + (size_t)(w * 64) * 8;
            unsigned short* lbase2 = sS1h + (size_t)(w * 64) * 8;
            unsigned short* lbase3 = sS1l + (size_t)(w * 64) * 8;
            gl2lds16(C1h + ga, lbase0);
            gl2lds16(C1l + ga, lbase1);
            gl2lds16(S1h + ga, lbase2);
            gl2lds16(S1l + ga, lbase3);
        }
        // Y: matrix chosen by w>>1, half by w&1 (each 2 calls of 64 slots)
        {
            int m = w >> 1, p = w & 1;
            const unsigned short* yg;
            unsigned short* yl;
            if (m == 0)      { yg = Ych; yl = sYch; }
            else if (m == 1) { yg = Ycl; yl = sYcl; }
            else if (m == 2) { yg = Ysh; yl = sYsh; }
            else             { yg = Ysl; yl = sYsl; }
            size_t gb = (size_t)n0 * KF + kk0;
#pragma unroll
            for (int s = 0; s < 2; s++) {
                int slot = p * 128 + s * 64;
                int sl = slot + lane;
                int row = sl >> 2, gc = (sl & 3) ^ ((row >> 1) & 3);
                gl2lds16(yg + gb + (size_t)row * KF + gc * 8, yl + slot * 8);
            }
        }
        __syncthreads();
        int q = lane >> 4;
        short8 bch[2], bcl[2], bsh[2], bsl[2];
#pragma unroll
        for (int j = 0; j < 2; j++) {
            int r2 = wc + j * 16 + (lane & 15);
            bch[j] = ld8x32(sYch, r2, q); bcl[j] = ld8x32(sYcl, r2, q);
            bsh[j] = ld8x32(sYsh, r2, q); bsl[j] = ld8x32(sYsl, r2, q);
        }
#pragma unroll
        for (int i = 0; i < 2; i++) {
            int r1 = wr + i * 16 + (lane & 15);
            short8 ach = ld8x32(sC1h, r1, q), acl = ld8x32(sC1l, r1, q);
            short8 ash = ld8x32(sS1h, r1, q), asl = ld8x32(sS1l, r1, q);
#pragma unroll
            for (int j = 0; j < 2; j++) {
                MFMA16(U[i][j], ach, bch[j]);
                MFMA16(U[i][j], ach, bcl[j]);
                MFMA16(U[i][j], acl, bch[j]);
                MFMA16(V[i][j], ash, bsh[j]);
                MFMA16(V[i][j], ash, bsl[j]);
                MFMA16(V[i][j], asl, bsh[j]);
            }
        }
        __syncthreads();
    }
    int q4 = (lane >> 4) * 4;
#pragma unroll
    for (int j = 0; j < 2; j++) {
        int rcol = n0 + wc + j * 16 + (lane & 15);
        int b = rcol / MF, mm = rcol - b * MF;
        float* tb = t + (size_t)b * NTOK * DIM;
        if (mm > 128) continue;
#pragma unroll
        for (int i = 0; i < 2; i++) {
            int kk = k0m + wr + i * 16 + q4;
#pragma unroll
            for (int g = 0; g < 4; g++) {
                int k = kk + g;
                if (k > 512) continue;
                float u = U[i][j][g], v = V[i][j][g];
                tb[(size_t)k * 256 + mm] += u - v;
                if (mm >= 1 && mm <= 127) tb[(size_t)k * 256 + 256 - mm] += u + v;
                if (k >= 1) {
                    tb[(size_t)(NTOK - k) * 256 + mm] += u + v;
                    if (mm >= 1 && mm <= 127) tb[(size_t)(NTOK - k) * 256 + 256 - mm] += u - v;
                }
            }
        }
    }
}

// ---------------------------------------------------------------------------
// Fused FFN v5: t += leaky(hh @ w1 + b1) @ w2 + b2.  M-tile 128, 512 threads.
// H-chunk 64 (16 chunks). LDS: 3 rotating 32KB weight buffers + sH 16KB = 112KB
// -> 1 blk/CU (uniform progress => weight reads stay L2-hot).
// Pipeline per chunk: [BarX] issue w1(hc+1)->free; GEMM1; sH; [BarY] issue
// w2(hc+1)->old-w1; GEMM2.  NEW vs v3: tail block (m0=65536, 64 real rows)
// skips dead compute via wave-uniform guards (wr1/wr2 < mloc) -> tail T ~0.6x,
// makespan 2T + 0.6T instead of 3T. Guards never fire for blocks 0..511.
// Accumulation h-order identical to v1-v3 -> bit-identical output.
__global__ __launch_bounds__(512, 2) void gemm_ffn_fused(
    const unsigned short* __restrict__ A, const unsigned short* __restrict__ W1t,
    const float* __restrict__ b1, const unsigned short* __restrict__ W2t,
    const float* __restrict__ b2, float* __restrict__ t) {
    __shared__ __align__(16) unsigned short sBuf[3][16384];  // 3 x 32 KB
    __shared__ __align__(16) unsigned short sH[8192];        // 16 KB: [128][64]
    int m0 = blockIdx.x * 128;
    int mloc = MROWS - m0;                 // rows this block owns (>=128 except tail: 64)
    int tid = threadIdx.x, lane = tid & 63, w = tid >> 6;
    // GEMM1 wave layout: 8 waves over 128x64 -> 32 rows x 32 cols each
    int wr1 = (w >> 1) * 32, wc1 = (w & 1) * 32;
    // GEMM2 wave layout: 8 waves over 128x256 -> 64 rows x 64 cols each
    int wr2 = (w >> 2) * 64, wc2 = (w & 3) * 64;
    bool act1 = (wr1 < mloc);              // wave-uniform; always true except tail waves
    bool act2 = (wr2 < mloc);
    // w1 panel stage coords: 512 slots (64 rows x 8 granules), 1 slot/thread/panel
    int prow = tid >> 3, pgc = (tid & 7) ^ (prow & 7);
    // A rows for GEMM1 into registers (clamped for M-tail; epilogue guards)
    short8 areg[2][8];
#pragma unroll
    for (int i = 0; i < 2; i++) {
        int rr = m0 + wr1 + i * 16 + (lane & 15);
        if (rr > MROWS - 1) rr = MROWS - 1;
        const unsigned short* ap = A + (size_t)rr * 256 + (lane >> 4) * 8;
#pragma unroll
        for (int p = 0; p < 4; p++)
#pragma unroll
            for (int kc = 0; kc < 2; kc++)
                areg[i][p * 2 + kc] = *(const short8*)(ap + p * 64 + kc * 32);
    }
    f32x4 z = {0.f, 0.f, 0.f, 0.f};
    f32x4 acc2[4][4] = {{z, z, z, z}, {z, z, z, z}, {z, z, z, z}, {z, z, z, z}};
    int q4 = (lane >> 4) * 4;
    unsigned short* bw1 = sBuf[0];
    unsigned short* bw2 = sBuf[1];
    unsigned short* bfr = sBuf[2];
    // prologue: stage w1(0), w2(0)
#pragma unroll
    for (int p = 0; p < 4; p++)
        gl2lds16(W1t + (size_t)prow * 256 + p * 64 + pgc * 8, bw1 + p * 4096 + (w * 64) * 8);
#pragma unroll
    for (int rb = 0; rb < 2; rb++)
        a_stage128_512(bw2 + rb * 8192, W2t + (size_t)(rb * 128) * 1024, 1024, tid, 127);
    for (int hc = 0; hc < 16; hc++) {
        int h0 = hc * 64;
        __syncthreads();   // BarX: w1(hc) in bw1, w2(hc) in bw2 ready; bfr free
        // issue w1(hc+1) -> bfr (hidden under GEMM1)
        if (hc < 15) {
            const unsigned short* wsrc = W1t + (size_t)(h0 + 64 + prow) * 256;
#pragma unroll
            for (int p = 0; p < 4; p++)
                gl2lds16(wsrc + p * 64 + pgc * 8, bfr + p * 4096 + (w * 64) * 8);
        }
        if (act1) {
            // GEMM1: acc1 = A(regs) x w1-chunk (64 H-cols) from bw1
            f32x4 acc1[2][2] = {{z, z}, {z, z}};
#pragma unroll
            for (int p = 0; p < 4; p++)
#pragma unroll
                for (int kc = 0; kc < 2; kc++) {
                    int q = (lane >> 4) + kc * 4;
                    short8 bh[2];
#pragma unroll
                    for (int j = 0; j < 2; j++)
                        bh[j] = ld8x64(bw1 + p * 4096, wc1 + j * 16 + (lane & 15), q);
#pragma unroll
                    for (int i = 0; i < 2; i++)
#pragma unroll
                        for (int j = 0; j < 2; j++) MFMA16(acc1[i][j], areg[i][p * 2 + kc], bh[j]);
                }
            // bias + leaky + bf16 -> sH
#pragma unroll
            for (int j = 0; j < 2; j++) {
                int col = wc1 + j * 16 + (lane & 15);
                float bv = b1[h0 + col];
#pragma unroll
                for (int i = 0; i < 2; i++)
#pragma unroll
                    for (int g = 0; g < 4; g++) {
                        int row = wr1 + i * 16 + q4 + g;
                        float val = acc1[i][j][g] + bv;
                        val = val > 0.f ? val : 0.01f * val;
                        sH[(row * 8 + ((col >> 3) ^ (row & 7))) * 8 + (col & 7)] = rne_bf16(val);
                    }
            }
        }
        __syncthreads();   // BarY: sH ready; w1(hc+1) drained into bfr
        // issue w2(hc+1) -> bw1 (GEMM1 done with it; hidden under GEMM2)
        if (hc < 15) {
#pragma unroll
            for (int rb = 0; rb < 2; rb++)
                a_stage128_512(bw1 + rb * 8192, W2t + (size_t)(rb * 128) * 1024 + h0 + 64, 1024, tid, 127);
        }
        if (act2) {
            // GEMM2: acc2 += sH x w2-chunk from bw2
#pragma unroll
            for (int kc = 0; kc < 2; kc++) {
                int q = (lane >> 4) + kc * 4;
                short8 ah[4], bh[4];
#pragma unroll
                for (int i = 0; i < 4; i++)
                    ah[i] = ld8x64(sH, wr2 + i * 16 + (lane & 15), q);
#pragma unroll
                for (int j = 0; j < 4; j++) {
                    int n = wc2 + j * 16 + (lane & 15);
                    bh[j] = ld8x64(bw2 + (n >> 7) * 8192, n & 127, q);
                }
#pragma unroll
                for (int i = 0; i < 4; i++)
#pragma unroll
                    for (int j = 0; j < 4; j++) MFMA16(acc2[i][j], ah[i], bh[j]);
            }
        }
        // rotate: next w1 = bfr, next w2 = old bw1 (w2(hc+1)), free = old bw2
        unsigned short* t0 = bw1;
        bw1 = bfr; bfr = bw2; bw2 = t0;
    }
#pragma unroll
    for (int i = 0; i < 4; i++) {
        int r = m0 + wr2 + i * 16 + q4;
#pragma unroll
        for (int j = 0; j < 4; j++) {
            int c = wc2 + j * 16 + (lane & 15);
            float bv = b2[c];
#pragma unroll
            for (int g = 0; g < 4; g++) {
                int rr = r + g;
                if (rr < MROWS) t[(size_t)rr * 256 + c] += acc2[i][j][g] + bv;
            }
        }
    }
}

// ---------------------------------------------------------------------------
__global__ __launch_bounds__(256) void head_kernel(const float* __restrict__ t,
                                                   const float* __restrict__ hs, const float* __restrict__ hb,
                                                   const float* __restrict__ hw, const float* __restrict__ hbias,
                                                   float* __restrict__ out) {
    __shared__ float red[256];
    __shared__ float lnv[256];
    int b = blockIdx.x, tid = threadIdx.x;
    const float* tb = t + (size_t)b * NTOK * DIM;
    float s = 0.f;
    for (int m = 0; m < NTOK; m++) s += tb[m * DIM + tid];
    s *= (1.f / 1025.f);
    red[tid] = s;
    __syncthreads();
    for (int off = 128; off; off >>= 1) {
        if (tid < off) red[tid] += red[tid + off];
        __syncthreads();
    }
    float mean = red[0] * (1.f / 256.f);
    __syncthreads();
    float d = s - mean;
    red[tid] = d * d;
    __syncthreads();
    for (int off = 128; off; off >>= 1) {
        if (tid < off) red[tid] += red[tid + off];
        __syncthreads();
    }
    float rstd = rsqrtf(red[0] * (1.f / 256.f) + LN_EPS);
    __syncthreads();
    lnv[tid] = d * rstd * hs[tid] + hb[tid];
    __syncthreads();
    float lo[4];
#pragma unroll
    for (int jj = 0; jj < 4; jj++) {
        int n = tid + jj * 256;
        float a = -1e30f;
        if (n < NCLS) {
            a = hbias[n];
            for (int dd = 0; dd < DIM; dd++) a += lnv[dd] * hw[dd * NCLS + n];
        }
        lo[jj] = a;
    }
    float mx = fmaxf(fmaxf(lo[0], lo[1]), fmaxf(lo[2], lo[3]));
    red[tid] = mx;
    __syncthreads();
    for (int off = 128; off; off >>= 1) {
        if (tid < off) red[tid] = fmaxf(red[tid], red[tid + off]);
        __syncthreads();
    }
    float gmax = red[0];
    __syncthreads();
    float ev[4];
    float es = 0.f;
#pragma unroll
    for (int jj = 0; jj < 4; jj++) {
        int n = tid + jj * 256;
        ev[jj] = 0.f;
        if (n < NCLS) {
            ev[jj] = expf(lo[jj] - gmax);
            es += ev[jj];
        }
    }
    red[tid] = es;
    __syncthreads();
    for (int off = 128; off; off >>= 1) {
        if (tid < off) red[tid] += red[tid + off];
        __syncthreads();
    }
    float inv = 1.f / red[0];
#pragma unroll
    for (int jj = 0; jj < 4; jj++) {
        int n = tid + jj * 256;
        if (n < NCLS) out[(size_t)b * NCLS + n] = ev[jj] * inv;
    }
}

// ---------------------------------------------------------------------------
extern "C" void kernel_launch(void* const* d_in, const int* in_sizes, int n_in,
                              void* d_out, int out_size, void* d_ws, size_t ws_size,
                              hipStream_t stream) {
    const float* x      = (const float*)d_in[0];
    const float* conv_w = (const float*)d_in[1];
    const float* conv_b = (const float*)d_in[2];
    const float* pos    = (const float*)d_in[3];
    const float* cls    = (const float*)d_in[4];
    const float* ln1_s  = (const float*)d_in[5];
    const float* ln1_b  = (const float*)d_in[6];
    const float* ln2_s  = (const float*)d_in[7];
    const float* ln2_b  = (const float*)d_in[8];
    const float* w1     = (const float*)d_in[9];
    const float* b1     = (const float*)d_in[10];
    const float* w2     = (const float*)d_in[11];
    const float* b2     = (const float*)d_in[12];
    const float* hls    = (const float*)d_in[13];
    const float* hlb    = (const float*)d_in[14];
    const float* hw     = (const float*)d_in[15];
    const float* hbias  = (const float*)d_in[16];
    float* out = (float*)d_out;
    char* W = (char*)d_ws;

    // layout (bytes), pool time-multiplexed:
    //   t:    [0, 67,174,400)
    //   pool @ 67,174,400 (167,936,000):
    //     Yct @ +75,497,472 (4 x 10,616,832)      — phase A  (ends +117,964,800)
    //     hh  @ +134,348,800 (33,587,200)         — phase B
    //   C1 grp @ 235,110,400 (4 x 737,280 = 640x576x2)
    //   C2 grp @ 238,059,520 (4 x 131,072)
    //   w1t @ 238,583,808 | w2t @ 241,729,536 | wph @ 244,875,264 | wpl @ 245,268,480
    //   stats @ 245,661,696 (65600 x 8B = 524,800)
    float*          t    = (float*)(W + 0ULL);
    char*           pool = W + 67174400ULL;
    unsigned short* Ycth = (unsigned short*)(pool + 75497472ULL);
    unsigned short* Yctl = (unsigned short*)(pool + 75497472ULL + 10616832ULL);
    unsigned short* Ysth = (unsigned short*)(pool + 75497472ULL + 2 * 10616832ULL);
    unsigned short* Ystl = (unsigned short*)(pool + 75497472ULL + 3 * 10616832ULL);
    unsigned short* hh   = (unsigned short*)(pool + 134348800ULL);
    unsigned short* C1h  = (unsigned short*)(W + 235110400ULL);
    unsigned short* C1l  = (unsigned short*)(W + 235110400ULL + 737280ULL);
    unsigned short* S1h  = (unsigned short*)(W + 235110400ULL + 2 * 737280ULL);
    unsigned short* S1l  = (unsigned short*)(W + 235110400ULL + 3 * 737280ULL);
    unsigned short* C2h  = (unsigned short*)(W + 238059520ULL);
    unsigned short* C2l  = (unsigned short*)(W + 238059520ULL + 131072ULL);
    unsigned short* S2h  = (unsigned short*)(W + 238059520ULL + 2 * 131072ULL);
    unsigned short* S2l  = (unsigned short*)(W + 238059520ULL + 3 * 131072ULL);
    unsigned short* w1t  = (unsigned short*)(W + 238583808ULL);
    unsigned short* w2t  = (unsigned short*)(W + 241729536ULL);
    unsigned short* wph  = (unsigned short*)(W + 244875264ULL);
    unsigned short* wpl  = (unsigned short*)(W + 245268480ULL);
    float2*         stats = (float2*)(W + 245661696ULL);

    gen_dft2<<<dim3(1440), dim3(256), 0, stream>>>(C1h, C1l, S1h, S1l, C2h, C2l, S2h, S2l);
    conv_wp<<<dim3(768), dim3(256), 0, stream>>>(conv_w, wph, wpl);
    conv_w1t<<<dim3(6144), dim3(256), 0, stream>>>(w1, w1t);
    conv_w2t<<<dim3(6144), dim3(256), 0, stream>>>(w2, w2t);
    cls_init<<<dim3(BATCH), dim3(256), 0, stream>>>(cls, pos, t);
    patch_fused<<<dim3(512, 2), dim3(256), 0, stream>>>(x, wph, wpl, conv_b, pos, t);

    for (int l = 0; l < NLAYER; l++) {
        ln_stats<<<dim3(16400), dim3(256), 0, stream>>>(t, stats);
        fold_gemm<<<dim3(288, 2), dim3(256), 0, stream>>>(
            t, stats, ln1_s + l * DIM, ln1_b + l * DIM,
            C2h, C2l, S2h, S2l, Ycth, Yctl, Ysth, Ystl);
        fft_big_dual<<<dim3(720), dim3(512), 0, stream>>>(
            C1h, C1l, S1h, S1l, Ycth, Yctl, Ysth, Ystl, t);
        ln2_bf16<<<dim3(16400), dim3(256), 0, stream>>>(t, hh, ln2_s + l * DIM, ln2_b + l * DIM);
        gemm_ffn_fused<<<dim3(513), dim3(512), 0, stream>>>(
            hh, w1t + (size_t)l * 262144, b1 + (size_t)l * HID,
            w2t + (size_t)l * 262144, b2 + (size_t)l * DIM, t);
    }
    head_kernel<<<dim3(BATCH), dim3(256), 0, stream>>>(t, hls, hlb, hw, hbias, out);
}